// Round 4
// baseline (669.861 us; speedup 1.0000x reference)
//
#include <hip/hip_runtime.h>
#include <hip/hip_bf16.h>

// Problem constants
#define B_   64
#define N_   512
#define D_   256
#define H_   4
#define HD_  64

typedef __hip_bfloat16 bf16;
typedef __attribute__((ext_vector_type(8))) short short8;
typedef __attribute__((ext_vector_type(4))) float floatx4;

__device__ __forceinline__ float bf2f(bf16 v) { return __bfloat162float(v); }
__device__ __forceinline__ unsigned short f2us(float f) {
    bf16 h = __float2bfloat16(f);
    union { bf16 h; unsigned short u; } c; c.h = h; return c.u;
}

// async 16B global -> LDS DMA (gfx950). LDS dest must be wave-uniform base +
// lane*16 -- our per-lane pointers are lane-contiguous by construction.
typedef __attribute__((address_space(1))) const unsigned int asg_u32;
typedef __attribute__((address_space(3))) unsigned int asl_u32;
__device__ __forceinline__ void gl_lds16(const void* g, void* l) {
    __builtin_amdgcn_global_load_lds((asg_u32*)g, (asl_u32*)l, 16, 0, 0);
}

// ---------------------------------------------------------------------------
// Weight pre-convert: fp32 -> bf16, zero-padded rows Kreal -> Kp (K%32==0).
// dst layout: Wr[256*800] Wf[256*704] Wq Wk Wv Wo W1 W2 [256*256 each].
// ---------------------------------------------------------------------------
__global__ __launch_bounds__(256)
void convw_k(const float* __restrict__ Wr, const float* __restrict__ Wf,
             const float* __restrict__ Wq, const float* __restrict__ Wk,
             const float* __restrict__ Wv, const float* __restrict__ Wo,
             const float* __restrict__ W1, const float* __restrict__ W2,
             bf16* __restrict__ dst)
{
    const int seg = blockIdx.y;
    const float* src; int Kreal, Kp; size_t off;
    switch (seg) {
        case 0: src = Wr; Kreal = 769; Kp = 800; off = 0; break;
        case 1: src = Wf; Kreal = 674; Kp = 704; off = 256 * 800; break;
        default:
            src = (seg == 2) ? Wq : (seg == 3) ? Wk : (seg == 4) ? Wv
                : (seg == 5) ? Wo : (seg == 6) ? W1 : W2;
            Kreal = 256; Kp = 256;
            off = 256 * 800 + 256 * 704 + (size_t)(seg - 2) * 256 * 256;
            break;
    }
    const int idx = blockIdx.x * 256 + threadIdx.x;   // unit = 8 outputs
    if (idx >= 256 * Kp / 8) return;
    const int rowk = idx * 8;
    const int n = rowk / Kp, k0 = rowk % Kp;
    unsigned short tmp[8];
    #pragma unroll
    for (int j = 0; j < 8; ++j) {
        int kk = k0 + j;
        tmp[j] = f2us(kk < Kreal ? src[(size_t)n * Kreal + kk] : 0.f);
    }
    *(short8*)&dst[off + (size_t)rowk] = *(short8*)tmp;
}

// ---------------------------------------------------------------------------
// Positional-embedding table: pe[n][c], n<512, c<256. grid 512 x 256 thr.
// ---------------------------------------------------------------------------
__global__ __launch_bounds__(256)
void pe_k(float* __restrict__ pe)
{
    const int n = blockIdx.x, c = threadIdx.x;
    const int j = c & ~1;
    float freq = __expf(-(float)j * (9.210340371976184f / 256.0f)); // ln(10000)/d
    float ang = (float)n * freq;
    pe[n * 256 + c] = (c & 1) ? cosf(ang) : sinf(ang);
}

// ---------------------------------------------------------------------------
// MFMA GEMM, 32x256 row-panel tile, BK=32, ONE barrier per K-step.
// grid = 1024 blocks (4/CU), LDS 37 KB -> 4 blocks/CU resident.
// Epilogue fuses bias/PE/ReLU/residual/LayerNorm/mean-pool-partials or
// writes V transposed (tv).
// F32A=true: A is raw fp32 (row stride Kreal); per-thread 4-float reg
//   prefetch one tile ahead, cvt+ds_write into the ping-pong As while the
//   other buffer is consumed. Bounds guard hoisted to the last K-tile only.
// F32A=false: A staged via global_load_lds double-buffer.
//   A-tile = 32 rows x 32 k = 2 KB = 128 lanes x 16B -> waves 0-1 only
//   (wave w stages k-groups {2w, 2w+1}; LDS dest = base + lane*16).
// ---------------------------------------------------------------------------
template<bool F32A>
__global__ __launch_bounds__(256)
void gemm_rp_t(const bf16* __restrict__ A, const float* __restrict__ A32,
               int lda, int Kreal,
               const bf16* __restrict__ W, int ldw,
               const float* __restrict__ bias, const bf16* __restrict__ res,
               const float* __restrict__ pe,
               const float* __restrict__ g, const float* __restrict__ bln,
               bf16* __restrict__ C, float* __restrict__ pp,
               int Kp, int relu, int tv)
{
    __shared__ bf16 As[2][4 * 32 * 8];     //  4 KB
    __shared__ bf16 Bs[2][4 * 256 * 8];    // 32 KB
    __shared__ float s_mu[32][4], s_sq[32][4]; // 1 KB (LN cross-wave reduce)

    const int tid = threadIdx.x;
    const int m0 = blockIdx.x * 32;
    const int lane = tid & 63, w = tid >> 6;
    const int fr = lane & 15, quad = lane >> 4;
    const int nt = Kp / 32;

    const unsigned short* Wp = (const unsigned short*)W + (size_t)lane * ldw + w * 8;

    floatx4 acc[2][4] = {};
    int cur = 0;

    if constexpr (F32A) {
        // per-thread: 4 floats of one (row, k-sub) slot; 256 thr cover 32x32
        const int srow = (tid >> 3) & 31;
        const int ksub = tid & 7;            // k-offset ksub*4
        const int g4 = ksub >> 1;            // k-group (8 elems)
        const int sub = (ksub & 1) * 4;
        const float* a32p = A32 + (size_t)(m0 + srow) * Kreal + ksub * 4;
        float av[4];

        // tile 0 (always full: Kreal >= 256)
        #pragma unroll
        for (int j = 0; j < 4; ++j) av[j] = a32p[j];
        #pragma unroll
        for (int i = 0; i < 4; ++i)
            gl_lds16(Wp + (size_t)(i * 64) * ldw, &Bs[0][(w * 256 + i * 64 + lane) * 8]);
        {
            unsigned short uw[4];
            #pragma unroll
            for (int j = 0; j < 4; ++j) uw[j] = f2us(av[j]);
            *(ushort4*)&As[0][(g4 * 32 + srow) * 8 + sub] = *(ushort4*)uw;
        }
        if (nt > 1) {
            const int kL = 32;
            if (kL + 32 <= Kreal) {
                #pragma unroll
                for (int j = 0; j < 4; ++j) av[j] = a32p[kL + j];
            } else {
                #pragma unroll
                for (int j = 0; j < 4; ++j) {
                    int kk = kL + ksub * 4 + j;
                    av[j] = (kk < Kreal) ? a32p[kL + j] : 0.f;
                }
            }
        }

        for (int t = 0; t < nt; ++t) {
            __syncthreads();   // drains B DMA(cur) + av loads; As[cur] writes visible
            const int nb = cur ^ 1;
            if (t + 1 < nt) {
                const int kB = (t + 1) * 32;
                #pragma unroll
                for (int i = 0; i < 4; ++i)
                    gl_lds16(Wp + (size_t)(i * 64) * ldw + kB,
                             &Bs[nb][(w * 256 + i * 64 + lane) * 8]);
                unsigned short uw[4];
                #pragma unroll
                for (int j = 0; j < 4; ++j) uw[j] = f2us(av[j]);
                *(ushort4*)&As[nb][(g4 * 32 + srow) * 8 + sub] = *(ushort4*)uw;
                if (t + 2 < nt) {
                    const int kL = (t + 2) * 32;
                    if (kL + 32 <= Kreal) {
                        #pragma unroll
                        for (int j = 0; j < 4; ++j) av[j] = a32p[kL + j];
                    } else {
                        #pragma unroll
                        for (int j = 0; j < 4; ++j) {
                            int kk = kL + ksub * 4 + j;
                            av[j] = (kk < Kreal) ? a32p[kL + j] : 0.f;
                        }
                    }
                }
            }
            short8 a[2];
            #pragma unroll
            for (int im = 0; im < 2; ++im)
                a[im] = *(const short8*)&As[cur][(quad * 32 + im * 16 + fr) * 8];
            #pragma unroll
            for (int in = 0; in < 4; ++in) {
                short8 bfrag = *(const short8*)&Bs[cur][(quad * 256 + w * 64 + in * 16 + fr) * 8];
                #pragma unroll
                for (int im = 0; im < 2; ++im)
                    acc[im][in] = __builtin_amdgcn_mfma_f32_16x16x32_bf16(
                        a[im], bfrag, acc[im][in], 0, 0, 0);
            }
            cur ^= 1;
        }
    } else {
        // A stage: waves 0-1 only. wave w stages k-groups {2w, 2w+1} x 32 rows.
        // LDS byte addr = (ag*32 + arow)*16 = wave_base + lane*16 (contiguous).
        const int arow = lane & 31, ag = (w & 1) * 2 + (lane >> 5);
        const bool doA = (w < 2);
        const unsigned short* Ap = (const unsigned short*)A + (size_t)(m0 + arow) * lda + ag * 8;
        bf16* AsD0 = &As[0][(ag * 32 + arow) * 8];
        bf16* AsD1 = &As[1][(ag * 32 + arow) * 8];

        if (doA) gl_lds16(Ap, AsD0);
        #pragma unroll
        for (int i = 0; i < 4; ++i)
            gl_lds16(Wp + (size_t)(i * 64) * ldw, &Bs[0][(w * 256 + i * 64 + lane) * 8]);

        for (int t = 0; t < nt; ++t) {
            __syncthreads();   // drains DMA for buf[cur]; prior reads of buf[cur^1] done
            const int nb = cur ^ 1;
            if (t + 1 < nt) {
                const int kB = (t + 1) * 32;
                if (doA) gl_lds16(Ap + kB, nb ? AsD1 : AsD0);
                #pragma unroll
                for (int i = 0; i < 4; ++i)
                    gl_lds16(Wp + (size_t)(i * 64) * ldw + kB,
                             &Bs[nb][(w * 256 + i * 64 + lane) * 8]);
            }
            short8 a[2];
            #pragma unroll
            for (int im = 0; im < 2; ++im)
                a[im] = *(const short8*)&As[cur][(quad * 32 + im * 16 + fr) * 8];
            #pragma unroll
            for (int in = 0; in < 4; ++in) {
                short8 bfrag = *(const short8*)&Bs[cur][(quad * 256 + w * 64 + in * 16 + fr) * 8];
                #pragma unroll
                for (int im = 0; im < 2; ++im)
                    acc[im][in] = __builtin_amdgcn_mfma_f32_16x16x32_bf16(
                        a[im], bfrag, acc[im][in], 0, 0, 0);
            }
            cur ^= 1;
        }
    }

    // ---- epilogue: bias (+pe) (+relu) (+res), all in fp32 regs ----
    // C/D layout: col = lane&15 (fr), row = quad*4 + reg
    #pragma unroll
    for (int in = 0; in < 4; ++in) {
        const int n = w * 64 + in * 16 + fr;
        const float bi = bias[n];
        #pragma unroll
        for (int im = 0; im < 2; ++im) {
            #pragma unroll
            for (int reg = 0; reg < 4; ++reg) {
                const int m = m0 + im * 16 + quad * 4 + reg;
                float v = acc[im][in][reg] + bi;
                if (pe)   v += pe[((m & (N_ - 1)) << 8) + n];
                if (relu) v = fmaxf(v, 0.f);
                if (res)  v += bf2f(res[((size_t)m << 8) + n]);
                acc[im][in][reg] = v;
            }
        }
    }

    if (g) {
        // fused LayerNorm over the full row (256 cols spread across 4 waves)
        #pragma unroll
        for (int im = 0; im < 2; ++im) {
            #pragma unroll
            for (int reg = 0; reg < 4; ++reg) {
                float ps = acc[im][0][reg] + acc[im][1][reg]
                         + acc[im][2][reg] + acc[im][3][reg];
                float pq = acc[im][0][reg] * acc[im][0][reg]
                         + acc[im][1][reg] * acc[im][1][reg]
                         + acc[im][2][reg] * acc[im][2][reg]
                         + acc[im][3][reg] * acc[im][3][reg];
                #pragma unroll
                for (int off = 1; off < 16; off <<= 1) {
                    ps += __shfl_xor(ps, off, 64);
                    pq += __shfl_xor(pq, off, 64);
                }
                if (fr == 0) {
                    const int r = im * 16 + quad * 4 + reg;
                    s_mu[r][w] = ps;
                    s_sq[r][w] = pq;
                }
            }
        }
        __syncthreads();
        #pragma unroll
        for (int im = 0; im < 2; ++im) {
            #pragma unroll
            for (int reg = 0; reg < 4; ++reg) {
                const int r = im * 16 + quad * 4 + reg;
                const float mu = (s_mu[r][0] + s_mu[r][1] + s_mu[r][2] + s_mu[r][3])
                                 * (1.f / 256.f);
                const float var = (s_sq[r][0] + s_sq[r][1] + s_sq[r][2] + s_sq[r][3])
                                  * (1.f / 256.f) - mu * mu;
                const float rs = rsqrtf(var + 1e-5f);
                const int m = m0 + r;
                #pragma unroll
                for (int in = 0; in < 4; ++in) {
                    const int n = w * 64 + in * 16 + fr;
                    C[((size_t)m << 8) + n] = __float2bfloat16(
                        (acc[im][in][reg] - mu) * rs * g[n] + bln[n]);
                }
            }
        }
    } else if (tv) {
        // transposed V write: Vt[(b*4 + h)*64 + d][key=n], h = w, d = in*16+fr
        const int bh = ((m0 >> 9) << 2) + w;
        const int nn = m0 & (N_ - 1);
        unsigned short* Ct = (unsigned short*)C;
        #pragma unroll
        for (int in = 0; in < 4; ++in) {
            const int d = in * 16 + fr;
            #pragma unroll
            for (int im = 0; im < 2; ++im) {
                unsigned short pk[4];
                #pragma unroll
                for (int reg = 0; reg < 4; ++reg) pk[reg] = f2us(acc[im][in][reg]);
                *(ushort4*)&Ct[((size_t)(bh * 64 + d) << 9) + nn + im * 16 + quad * 4]
                    = *(ushort4*)pk;
            }
        }
    } else {
        #pragma unroll
        for (int im = 0; im < 2; ++im) {
            #pragma unroll
            for (int reg = 0; reg < 4; ++reg) {
                const int m = m0 + im * 16 + quad * 4 + reg;
                #pragma unroll
                for (int in = 0; in < 4; ++in) {
                    const int n = w * 64 + in * 16 + fr;
                    C[((size_t)m << 8) + n] = __float2bfloat16(acc[im][in][reg]);
                }
            }
        }
        if (pp) {
            // fused mean-pool partials: column sums over this block's 32 rows
            #pragma unroll
            for (int in = 0; in < 4; ++in) {
                float s = 0.f;
                #pragma unroll
                for (int im = 0; im < 2; ++im)
                    #pragma unroll
                    for (int reg = 0; reg < 4; ++reg) s += acc[im][in][reg];
                s += __shfl_xor(s, 16, 64);
                s += __shfl_xor(s, 32, 64);
                if (quad == 0)
                    pp[(size_t)blockIdx.x * 256 + w * 64 + in * 16 + fr] = s;
            }
        }
    }
}

// ---------------------------------------------------------------------------
// MFMA flash-style cross-attention. V comes in transposed (Vt[b,h][d][key]),
// so both K and V stage with conflict-free vectorized 16B writes. Q frags
// load straight from global (16B aligned). XCD-bijective block swizzle keeps
// each (b,h)'s K/V on one XCD's L2. Softmax in exp2 domain with folded scale.
// ---------------------------------------------------------------------------
__global__ __launch_bounds__(256)
void attn_k(const bf16* q, const bf16* __restrict__ k,
            const bf16* __restrict__ vt, bf16* ctx)
{
    __shared__ bf16 Ks[8 * 64 * 8];
    __shared__ bf16 Vs[8 * 64 * 8];
    __shared__ bf16 Ps[4 * 16 * 72];

    const int bid = blockIdx.x;
    const int l = (bid & 7) * 256 + (bid >> 3);   // XCD swizzle (2048 % 8 == 0)
    const int qt = l & 7;
    const int h  = (l >> 3) & 3;
    const int b  = l >> 5;
    const int q0 = qt * 64;
    const size_t base  = ((size_t)b * N_) * D_ + h * HD_;    // q/k/ctx
    const size_t vbase = ((size_t)(b * H_ + h) * HD_) * N_;  // Vt rows=d, cols=key

    const int tid = threadIdx.x;
    const int lane = tid & 63;
    const int w = tid >> 6;
    const int fr = lane & 15, quad = lane >> 4;

    // Q fragments direct from global (one-time, 16B aligned, L2-hot)
    short8 aq[2];
    #pragma unroll
    for (int ks = 0; ks < 2; ++ks)
        aq[ks] = *(const short8*)((const unsigned short*)q + base
                   + (size_t)(q0 + w * 16 + fr) * D_ + (ks * 4 + quad) * 8);

    floatx4 O[4] = {};
    float mrun[4], lrun[4];
    #pragma unroll
    for (int r = 0; r < 4; ++r) { mrun[r] = -1e30f; lrun[r] = 0.f; }

    const int srow = tid >> 2, sc = tid & 3;
    const unsigned short* kp = (const unsigned short*)k + base + (size_t)srow * D_ + sc * 16;
    const unsigned short* vp = (const unsigned short*)vt + vbase + (size_t)srow * N_ + sc * 16;
    const float C1 = 0.125f * 1.44269504f;  // scale * log2(e)

    for (int kt = 0; kt < 8; ++kt) {
        __syncthreads();
        {
            const unsigned short* srck = kp + (size_t)(kt * 64) * D_;
            *(short8*)&Ks[((sc * 2 + 0) * 64 + srow) * 8] = *(const short8*)(srck);
            *(short8*)&Ks[((sc * 2 + 1) * 64 + srow) * 8] = *(const short8*)(srck + 8);
            const unsigned short* srcv = vp + kt * 64;
            *(short8*)&Vs[((sc * 2 + 0) * 64 + srow) * 8] = *(const short8*)(srcv);
            *(short8*)&Vs[((sc * 2 + 1) * 64 + srow) * 8] = *(const short8*)(srcv + 8);
        }
        __syncthreads();

        floatx4 S[4] = {};
        __builtin_amdgcn_s_setprio(1);
        #pragma unroll
        for (int in = 0; in < 4; ++in) {
            #pragma unroll
            for (int ks = 0; ks < 2; ++ks) {
                short8 bk = *(const short8*)&Ks[((ks * 4 + quad) * 64 + in * 16 + fr) * 8];
                S[in] = __builtin_amdgcn_mfma_f32_16x16x32_bf16(aq[ks], bk, S[in], 0, 0, 0);
            }
        }
        __builtin_amdgcn_s_setprio(0);

        #pragma unroll
        for (int r = 0; r < 4; ++r) {
            float mloc = fmaxf(fmaxf(S[0][r], S[1][r]), fmaxf(S[2][r], S[3][r]));
            #pragma unroll
            for (int off = 1; off < 16; off <<= 1) mloc = fmaxf(mloc, __shfl_xor(mloc, off, 64));
            float mnew = fmaxf(mrun[r], mloc);
            float mc = mnew * C1;
            float alpha = exp2f(mrun[r] * C1 - mc);
            float rs = 0.f;
            #pragma unroll
            for (int in = 0; in < 4; ++in) {
                float p = exp2f(S[in][r] * C1 - mc);
                S[in][r] = p;
                rs += p;
            }
            #pragma unroll
            for (int off = 1; off < 16; off <<= 1) rs += __shfl_xor(rs, off, 64);
            lrun[r] = lrun[r] * alpha + rs;
            mrun[r] = mnew;
            #pragma unroll
            for (int in = 0; in < 4; ++in) O[in][r] *= alpha;
        }

        #pragma unroll
        for (int in = 0; in < 4; ++in)
            #pragma unroll
            for (int r = 0; r < 4; ++r)
                Ps[(w * 16 + quad * 4 + r) * 72 + in * 16 + fr] = __float2bfloat16(S[in][r]);
        short8 pa[2];
        #pragma unroll
        for (int ks = 0; ks < 2; ++ks)
            pa[ks] = *(const short8*)&Ps[(w * 16 + fr) * 72 + ks * 32 + quad * 8];

        __builtin_amdgcn_s_setprio(1);
        #pragma unroll
        for (int in = 0; in < 4; ++in) {
            #pragma unroll
            for (int ks = 0; ks < 2; ++ks) {
                short8 bv = *(const short8*)&Vs[((ks * 4 + quad) * 64 + in * 16 + fr) * 8];
                O[in] = __builtin_amdgcn_mfma_f32_16x16x32_bf16(pa[ks], bv, O[in], 0, 0, 0);
            }
        }
        __builtin_amdgcn_s_setprio(0);
    }

    #pragma unroll
    for (int r = 0; r < 4; ++r) {
        const float inv = 1.f / lrun[r];
        const int row = q0 + w * 16 + quad * 4 + r;
        #pragma unroll
        for (int in = 0; in < 4; ++in)
            ctx[base + (size_t)row * D_ + in * 16 + fr] = __float2bfloat16(O[in][r] * inv);
    }
}

// ---------------------------------------------------------------------------
// Mean-pool stage 2 + logits. grid B, block 256. out fp32 (B,2).
// partial: 16 chunks of 32 rows per batch.
// ---------------------------------------------------------------------------
__global__ __launch_bounds__(256)
void logits_k(const float* __restrict__ partial, const float* __restrict__ Wc,
              const float* __restrict__ bc, float* __restrict__ out)
{
    __shared__ float pl[256];
    __shared__ float red[256];
    int b = blockIdx.x, c = threadIdx.x;
    float s = 0.f;
    for (int ch = 0; ch < 16; ++ch) s += partial[((size_t)b * 16 + ch) * D_ + c];
    pl[c] = s * (1.f / 512.f);
    __syncthreads();
    int o = c >> 7, cc = c & 127;
    red[c] = pl[cc] * Wc[o * 256 + cc] + pl[cc + 128] * Wc[o * 256 + cc + 128];
    __syncthreads();
    for (int st = 64; st > 0; st >>= 1) { if (cc < st) red[c] += red[c + st]; __syncthreads(); }
    if (cc == 0) out[b * 2 + o] = red[c] + bc[o];
}

// ---------------------------------------------------------------------------
extern "C" void kernel_launch(void* const* d_in, const int* in_sizes, int n_in,
                              void* d_out, int out_size, void* d_ws, size_t ws_size,
                              hipStream_t stream)
{
    const float* x   = (const float*)d_in[0];
    const float* y   = (const float*)d_in[1];
    // d_in[2] = z, unused by the reference
    const float* Wr  = (const float*)d_in[3];
    const float* br  = (const float*)d_in[4];
    const float* Wf  = (const float*)d_in[5];
    const float* bfv = (const float*)d_in[6];
    const float* gx  = (const float*)d_in[7];
    const float* bx  = (const float*)d_in[8];
    const float* gy  = (const float*)d_in[9];
    const float* by  = (const float*)d_in[10];
    const float* Wq  = (const float*)d_in[11];
    const float* bq  = (const float*)d_in[12];
    const float* Wk  = (const float*)d_in[13];
    const float* bk  = (const float*)d_in[14];
    const float* Wv  = (const float*)d_in[15];
    const float* bv  = (const float*)d_in[16];
    const float* Wo  = (const float*)d_in[17];
    const float* bo  = (const float*)d_in[18];
    const float* gm  = (const float*)d_in[19];
    const float* bm  = (const float*)d_in[20];
    const float* W1  = (const float*)d_in[21];
    const float* b1  = (const float*)d_in[22];
    const float* W2  = (const float*)d_in[23];
    const float* b2  = (const float*)d_in[24];
    const float* Wc  = (const float*)d_in[25];
    const float* bc  = (const float*)d_in[26];

    bf16* ws = (bf16*)d_ws;
    const size_t S = (size_t)B_ * N_ * D_;          // 8,388,608 elems
    bf16*  wb   = ws;                                // weights: 778,240 elems
    float* pe   = (float*)(ws + 778240);             // 131,072 floats
    float* part = pe + 131072;                       // 262,144 floats (1024x256)
    bf16*  bA   = ws + 778240 + 6 * 131072;          // xp
    bf16*  bB   = bA + S;                            // yp -> final x_mlp
    bf16*  bC   = bB + S;                            // q  -> ctx (in-place)
    bf16*  bD   = bC + S;                            // k  -> x_res
    bf16*  bE   = bD + S;                            // Vt -> mlp hidden

    bf16* Wrb = wb;                                  // 256 x 800
    bf16* Wfb = wb + 256 * 800;                      // 256 x 704
    bf16* Wqb = Wfb + 256 * 704;
    bf16* Wkb = Wqb + 65536;
    bf16* Wvb = Wkb + 65536;
    bf16* Wob = Wvb + 65536;
    bf16* W1b = Wob + 65536;
    bf16* W2b = W1b + 65536;

    const int M = B_ * N_; // 32768 rows
    dim3 blk(256);
    dim3 grp(M / 32);                                // 1024 row-panel blocks

    // constants: PE table + weight conversion
    pe_k<<<N_, blk, 0, stream>>>(pe);
    convw_k<<<dim3(100, 8), blk, 0, stream>>>(Wr, Wf, Wq, Wk, Wv, Wo, W1, W2, wb);

    // xp = LN(x @ Wr.T + br + pe)   [fp32 A staged in-kernel, LN fused]
    gemm_rp_t<true><<<grp, blk, 0, stream>>>(nullptr, x, 0, 769, Wrb, 800,
        br, nullptr, pe, gx, bx, bA, nullptr, 800, 0, 0);
    // yp = LN(y @ Wf.T + bf + pe)
    gemm_rp_t<true><<<grp, blk, 0, stream>>>(nullptr, y, 0, 674, Wfb, 704,
        bfv, nullptr, pe, gy, by, bB, nullptr, 704, 0, 0);
    // q, k, v (v written transposed per (b,h): Vt[d][key])
    gemm_rp_t<false><<<grp, blk, 0, stream>>>(bA, nullptr, 256, 256, Wqb, 256,
        bq, nullptr, nullptr, nullptr, nullptr, bC, nullptr, 256, 0, 0);
    gemm_rp_t<false><<<grp, blk, 0, stream>>>(bB, nullptr, 256, 256, Wkb, 256,
        bk, nullptr, nullptr, nullptr, nullptr, bD, nullptr, 256, 0, 0);
    gemm_rp_t<false><<<grp, blk, 0, stream>>>(bB, nullptr, 256, 256, Wvb, 256,
        bv, nullptr, nullptr, nullptr, nullptr, bE, nullptr, 256, 0, 1);
    // attention -> ctx (in-place over q)
    attn_k<<<B_ * H_ * 8, blk, 0, stream>>>(bC, bD, bE, bC);
    // x_res = LN(xp + ctx @ Wo.T + bo)   [residual + LN fused]
    gemm_rp_t<false><<<grp, blk, 0, stream>>>(bC, nullptr, 256, 256, Wob, 256,
        bo, bA, nullptr, gm, bm, bD, nullptr, 256, 0, 0);
    // mlp
    gemm_rp_t<false><<<grp, blk, 0, stream>>>(bD, nullptr, 256, 256, W1b, 256,
        b1, nullptr, nullptr, nullptr, nullptr, bE, nullptr, 256, 1, 0);
    gemm_rp_t<false><<<grp, blk, 0, stream>>>(bE, nullptr, 256, 256, W2b, 256,
        b2, bD, nullptr, nullptr, nullptr, bB, part, 256, 0, 0);
    // logits
    logits_k<<<B_, blk, 0, stream>>>(part, Wc, bc, (float*)d_out);
}

// Round 6
// 549.891 us; speedup vs baseline: 1.2182x; 1.2182x over previous
//
#include <hip/hip_runtime.h>
#include <hip/hip_bf16.h>

// Problem constants
#define B_   64
#define N_   512
#define D_   256
#define H_   4
#define HD_  64

typedef __hip_bfloat16 bf16;
typedef __attribute__((ext_vector_type(8))) short short8;
typedef __attribute__((ext_vector_type(4))) float floatx4;

__device__ __forceinline__ float bf2f(bf16 v) { return __bfloat162float(v); }
__device__ __forceinline__ unsigned short f2us(float f) {
    bf16 h = __float2bfloat16(f);
    union { bf16 h; unsigned short u; } c; c.h = h; return c.u;
}

// async 16B global -> LDS DMA (gfx950). LDS dest must be wave-uniform base +
// lane*16 -- our per-lane pointers are lane-contiguous by construction.
typedef __attribute__((address_space(1))) const unsigned int asg_u32;
typedef __attribute__((address_space(3))) unsigned int asl_u32;
__device__ __forceinline__ void gl_lds16(const void* g, void* l) {
    __builtin_amdgcn_global_load_lds((asg_u32*)g, (asl_u32*)l, 16, 0, 0);
}

// counted waits (T4): keep next tile's loads in flight ACROSS the barrier.
__device__ __forceinline__ void wait_vm12() { asm volatile("s_waitcnt vmcnt(12)" ::: "memory"); }
__device__ __forceinline__ void wait_vm5()  { asm volatile("s_waitcnt vmcnt(5)"  ::: "memory"); }
__device__ __forceinline__ void wait_vm0()  { asm volatile("s_waitcnt vmcnt(0)"  ::: "memory"); }
__device__ __forceinline__ void wait_lg0()  { asm volatile("s_waitcnt lgkmcnt(0)" ::: "memory"); }
__device__ __forceinline__ void bar()       { __builtin_amdgcn_s_barrier(); }
__device__ __forceinline__ void schedb()    { __builtin_amdgcn_sched_barrier(0); }

// ---------------------------------------------------------------------------
// Weight pre-convert: fp32 -> bf16, zero-padded rows Kreal -> Kp (K%32==0).
// dst layout: Wr[256*800] Wf[256*704] Wq Wk Wv Wo W1 W2 [256*256 each].
// ---------------------------------------------------------------------------
__global__ __launch_bounds__(256)
void convw_k(const float* __restrict__ Wr, const float* __restrict__ Wf,
             const float* __restrict__ Wq, const float* __restrict__ Wk,
             const float* __restrict__ Wv, const float* __restrict__ Wo,
             const float* __restrict__ W1, const float* __restrict__ W2,
             bf16* __restrict__ dst)
{
    const int seg = blockIdx.y;
    const float* src; int Kreal, Kp; size_t off;
    switch (seg) {
        case 0: src = Wr; Kreal = 769; Kp = 800; off = 0; break;
        case 1: src = Wf; Kreal = 674; Kp = 704; off = 256 * 800; break;
        default:
            src = (seg == 2) ? Wq : (seg == 3) ? Wk : (seg == 4) ? Wv
                : (seg == 5) ? Wo : (seg == 6) ? W1 : W2;
            Kreal = 256; Kp = 256;
            off = 256 * 800 + 256 * 704 + (size_t)(seg - 2) * 256 * 256;
            break;
    }
    const int idx = blockIdx.x * 256 + threadIdx.x;   // unit = 8 outputs
    if (idx >= 256 * Kp / 8) return;
    const int rowk = idx * 8;
    const int n = rowk / Kp, k0 = rowk % Kp;
    unsigned short tmp[8];
    #pragma unroll
    for (int j = 0; j < 8; ++j) {
        int kk = k0 + j;
        tmp[j] = f2us(kk < Kreal ? src[(size_t)n * Kreal + kk] : 0.f);
    }
    *(short8*)&dst[off + (size_t)rowk] = *(short8*)tmp;
}

// ---------------------------------------------------------------------------
// Positional-embedding table: pe[n][c], n<512, c<256. grid 512 x 256 thr.
// ---------------------------------------------------------------------------
__global__ __launch_bounds__(256)
void pe_k(float* __restrict__ pe)
{
    const int n = blockIdx.x, c = threadIdx.x;
    const int j = c & ~1;
    float freq = __expf(-(float)j * (9.210340371976184f / 256.0f)); // ln(10000)/d
    float ang = (float)n * freq;
    pe[n * 256 + c] = (c & 1) ? cosf(ang) : sinf(ang);
}

// ---------------------------------------------------------------------------
// MFMA GEMM, 64x256 row-panel tile, BK=32, 3-buffer LDS, counted-vmcnt
// schedule: one raw s_barrier per K-step, next batch stays IN FLIGHT across
// it (wait vmcnt leaves exactly one batch outstanding; vmcnt(0) only on the
// last iteration). Epilogue fuses bias/PE/ReLU/residual/LN/pool or V^T.
// Per-wave batch = 12 vm-ops (F32A: 8 av loads + 4 B-DMA) or 5 (bf16:
// 1 A-DMA + 4 B-DMA); counts are exec-uniform (tail loads are clamped-
// address + select, never branched out).
// ---------------------------------------------------------------------------
template<bool F32A>
__global__ __launch_bounds__(256)
void gemm_rp_t(const bf16* __restrict__ A, const float* __restrict__ A32,
               int lda, int Kreal,
               const bf16* __restrict__ W, int ldw,
               const float* __restrict__ bias, const bf16* __restrict__ res,
               const float* __restrict__ pe,
               const float* __restrict__ g, const float* __restrict__ bln,
               bf16* __restrict__ C, float* __restrict__ pp,
               int Kp, int relu, int tv)
{
    __shared__ bf16 As[3][4 * 64 * 8];     // 12 KB
    __shared__ bf16 Bs[3][4 * 256 * 8];    // 48 KB
    __shared__ float s_mu[64][4], s_sq[64][4]; // 2 KB

    const int tid = threadIdx.x;
    const int m0 = blockIdx.x * 64;
    const int lane = tid & 63, w = tid >> 6;
    const int fr = lane & 15, quad = lane >> 4;
    const int nt = Kp / 32;

    const unsigned short* Wp = (const unsigned short*)W + (size_t)lane * ldw + w * 8;

    floatx4 acc[4][4] = {};
    int rb = 0, w1 = 1, w2 = 2;            // rotating buffer indices

    if constexpr (F32A) {
        // staging map: row = tid>>2 (64 rows), k-slot = (tid&3)*8
        const int srow = tid >> 2, skb = tid & 3, kb8 = skb * 8;
        const float* a32p = A32 + (size_t)(m0 + srow) * Kreal + kb8;
        float avA[8], avB[8];

        // prologue: tile 0 (av->regs, B->DMA, cvt->As[0]), tile 1 (av+B)
        #pragma unroll
        for (int j = 0; j < 8; ++j) avA[j] = a32p[j];           // 8 vm
        #pragma unroll
        for (int i = 0; i < 4; ++i)                              // 4 vm
            gl_lds16(Wp + (size_t)(i * 64) * ldw, &Bs[0][(w * 256 + i * 64 + lane) * 8]);
        {
            unsigned short uw[8];
            #pragma unroll
            for (int j = 0; j < 8; ++j) uw[j] = f2us(avA[j]);    // waits avA
            *(short8*)&As[0][(skb * 64 + srow) * 8] = *(short8*)uw;
        }
        #pragma unroll
        for (int j = 0; j < 8; ++j) avB[j] = a32p[32 + j];       // 8 vm
        #pragma unroll
        for (int i = 0; i < 4; ++i)                              // 4 vm
            gl_lds16(Wp + (size_t)(i * 64) * ldw + 32, &Bs[1][(w * 256 + i * 64 + lane) * 8]);

        // steady state: entering iter t, outstanding = B(t)-DMA tail +
        // batch(t+1). vm12 retires B(t); batch(t+1) stays in flight.
        auto f32a_step = [&](int t_, float (&AVC)[8], float (&AVN)[8]) {
            if (t_ + 1 < nt) { wait_vm12(); } else { wait_vm0(); }
            wait_lg0();
            bar();
            schedb();
            if (t_ + 2 < nt) {
                const int kL = (t_ + 2) * 32;
                if (kL + 32 <= Kreal) {
                    #pragma unroll
                    for (int j = 0; j < 8; ++j) AVN[j] = a32p[kL + j];
                } else {
                    #pragma unroll
                    for (int j = 0; j < 8; ++j) {
                        int kk = kL + kb8 + j;
                        int offv = (kk < Kreal) ? (kL + j) : 0;
                        float tvv = a32p[offv];
                        AVN[j] = (kk < Kreal) ? tvv : 0.f;
                    }
                }
                #pragma unroll
                for (int i = 0; i < 4; ++i)
                    gl_lds16(Wp + (size_t)(i * 64) * ldw + kL,
                             &Bs[w2][(w * 256 + i * 64 + lane) * 8]);
            }
            if (t_ + 1 < nt) {
                unsigned short uw[8];
                #pragma unroll
                for (int j = 0; j < 8; ++j) uw[j] = f2us(AVC[j]);
                *(short8*)&As[w1][(skb * 64 + srow) * 8] = *(short8*)uw;
            }
            schedb();
            short8 a[4];
            #pragma unroll
            for (int im = 0; im < 4; ++im)
                a[im] = *(const short8*)&As[rb][(quad * 64 + im * 16 + fr) * 8];
            #pragma unroll
            for (int in = 0; in < 4; ++in) {
                short8 bfrag = *(const short8*)&Bs[rb][(quad * 256 + w * 64 + in * 16 + fr) * 8];
                #pragma unroll
                for (int im = 0; im < 4; ++im)
                    acc[im][in] = __builtin_amdgcn_mfma_f32_16x16x32_bf16(
                        a[im], bfrag, acc[im][in], 0, 0, 0);
            }
            int tmp_ = rb; rb = w1; w1 = w2; w2 = tmp_;
        };
        for (int t = 0; t < nt; t += 2) {
            f32a_step(t, avB, avA);
            if (t + 1 < nt) f32a_step(t + 1, avA, avB);
        }
    } else {
        // A stage: wave w DMAs k-group w (1 op) + 4 B ops = 5/wave/batch.
        const unsigned short* Ap = (const unsigned short*)A + (size_t)(m0 + lane) * lda + w * 8;

        gl_lds16(Ap, &As[0][(w * 64 + lane) * 8]);
        #pragma unroll
        for (int i = 0; i < 4; ++i)
            gl_lds16(Wp + (size_t)(i * 64) * ldw, &Bs[0][(w * 256 + i * 64 + lane) * 8]);
        gl_lds16(Ap + 32, &As[1][(w * 64 + lane) * 8]);
        #pragma unroll
        for (int i = 0; i < 4; ++i)
            gl_lds16(Wp + (size_t)(i * 64) * ldw + 32, &Bs[1][(w * 256 + i * 64 + lane) * 8]);

        for (int t = 0; t < nt; ++t) {
            if (t + 1 < nt) { wait_vm5(); } else { wait_vm0(); }
            bar();
            schedb();
            if (t + 2 < nt) {
                const int kB = (t + 2) * 32;
                gl_lds16(Ap + kB, &As[w2][(w * 64 + lane) * 8]);
                #pragma unroll
                for (int i = 0; i < 4; ++i)
                    gl_lds16(Wp + (size_t)(i * 64) * ldw + kB,
                             &Bs[w2][(w * 256 + i * 64 + lane) * 8]);
            }
            schedb();
            short8 a[4];
            #pragma unroll
            for (int im = 0; im < 4; ++im)
                a[im] = *(const short8*)&As[rb][(quad * 64 + im * 16 + fr) * 8];
            #pragma unroll
            for (int in = 0; in < 4; ++in) {
                short8 bfrag = *(const short8*)&Bs[rb][(quad * 256 + w * 64 + in * 16 + fr) * 8];
                #pragma unroll
                for (int im = 0; im < 4; ++im)
                    acc[im][in] = __builtin_amdgcn_mfma_f32_16x16x32_bf16(
                        a[im], bfrag, acc[im][in], 0, 0, 0);
            }
            int tmp_ = rb; rb = w1; w1 = w2; w2 = tmp_;
        }
    }

    // ---- epilogue: bias (+pe) (+relu) (+res), all in fp32 regs ----
    // C/D layout: col = lane&15 (fr), row = quad*4 + reg
    #pragma unroll
    for (int in = 0; in < 4; ++in) {
        const int n = w * 64 + in * 16 + fr;
        const float bi = bias[n];
        #pragma unroll
        for (int im = 0; im < 4; ++im) {
            #pragma unroll
            for (int reg = 0; reg < 4; ++reg) {
                const int m = m0 + im * 16 + quad * 4 + reg;
                float v = acc[im][in][reg] + bi;
                if (pe)   v += pe[((m & (N_ - 1)) << 8) + n];
                if (relu) v = fmaxf(v, 0.f);
                if (res)  v += bf2f(res[((size_t)m << 8) + n]);
                acc[im][in][reg] = v;
            }
        }
    }

    if (g) {
        // fused LayerNorm over the full row (256 cols spread across 4 waves)
        #pragma unroll
        for (int im = 0; im < 4; ++im) {
            #pragma unroll
            for (int reg = 0; reg < 4; ++reg) {
                float ps = acc[im][0][reg] + acc[im][1][reg]
                         + acc[im][2][reg] + acc[im][3][reg];
                float pq = acc[im][0][reg] * acc[im][0][reg]
                         + acc[im][1][reg] * acc[im][1][reg]
                         + acc[im][2][reg] * acc[im][2][reg]
                         + acc[im][3][reg] * acc[im][3][reg];
                #pragma unroll
                for (int off = 1; off < 16; off <<= 1) {
                    ps += __shfl_xor(ps, off, 64);
                    pq += __shfl_xor(pq, off, 64);
                }
                if (fr == 0) {
                    const int r = im * 16 + quad * 4 + reg;
                    s_mu[r][w] = ps;
                    s_sq[r][w] = pq;
                }
            }
        }
        __syncthreads();
        #pragma unroll
        for (int im = 0; im < 4; ++im) {
            #pragma unroll
            for (int reg = 0; reg < 4; ++reg) {
                const int r = im * 16 + quad * 4 + reg;
                const float mu = (s_mu[r][0] + s_mu[r][1] + s_mu[r][2] + s_mu[r][3])
                                 * (1.f / 256.f);
                const float var = (s_sq[r][0] + s_sq[r][1] + s_sq[r][2] + s_sq[r][3])
                                  * (1.f / 256.f) - mu * mu;
                const float rs = rsqrtf(var + 1e-5f);
                const int m = m0 + r;
                #pragma unroll
                for (int in = 0; in < 4; ++in) {
                    const int n = w * 64 + in * 16 + fr;
                    C[((size_t)m << 8) + n] = __float2bfloat16(
                        (acc[im][in][reg] - mu) * rs * g[n] + bln[n]);
                }
            }
        }
    } else if (tv) {
        // transposed V write: Vt[(b*4 + h)*64 + d][key=n], h = w, d = in*16+fr
        const int bh = ((m0 >> 9) << 2) + w;
        const int nn = m0 & (N_ - 1);
        unsigned short* Ct = (unsigned short*)C;
        #pragma unroll
        for (int in = 0; in < 4; ++in) {
            const int d = in * 16 + fr;
            #pragma unroll
            for (int im = 0; im < 4; ++im) {
                unsigned short pk[4];
                #pragma unroll
                for (int reg = 0; reg < 4; ++reg) pk[reg] = f2us(acc[im][in][reg]);
                *(ushort4*)&Ct[((size_t)(bh * 64 + d) << 9) + nn + im * 16 + quad * 4]
                    = *(ushort4*)pk;
            }
        }
    } else {
        #pragma unroll
        for (int im = 0; im < 4; ++im) {
            #pragma unroll
            for (int reg = 0; reg < 4; ++reg) {
                const int m = m0 + im * 16 + quad * 4 + reg;
                #pragma unroll
                for (int in = 0; in < 4; ++in) {
                    const int n = w * 64 + in * 16 + fr;
                    C[((size_t)m << 8) + n] = __float2bfloat16(acc[im][in][reg]);
                }
            }
        }
        if (pp) {
            // fused mean-pool partials: column sums over this block's 64 rows
            #pragma unroll
            for (int in = 0; in < 4; ++in) {
                float s = 0.f;
                #pragma unroll
                for (int im = 0; im < 4; ++im)
                    #pragma unroll
                    for (int reg = 0; reg < 4; ++reg) s += acc[im][in][reg];
                s += __shfl_xor(s, 16, 64);
                s += __shfl_xor(s, 32, 64);
                if (quad == 0)
                    pp[((m0 >> 6) << 8) + w * 64 + in * 16 + fr] = s;
            }
        }
    }
}

// ---------------------------------------------------------------------------
// MFMA flash-style cross-attention. V comes in transposed (Vt[b,h][d][key]),
// so both K and V stage with conflict-free vectorized 16B writes. Q frags
// load straight from global (16B aligned). XCD-bijective block swizzle keeps
// each (b,h)'s K/V on one XCD's L2. Softmax in exp2 domain with folded scale.
// ---------------------------------------------------------------------------
__global__ __launch_bounds__(256)
void attn_k(const bf16* q, const bf16* __restrict__ k,
            const bf16* __restrict__ vt, bf16* ctx)
{
    __shared__ bf16 Ks[8 * 64 * 8];
    __shared__ bf16 Vs[8 * 64 * 8];
    __shared__ bf16 Ps[4 * 16 * 72];

    const int bid = blockIdx.x;
    const int l = (bid & 7) * 256 + (bid >> 3);   // XCD swizzle (2048 % 8 == 0)
    const int qt = l & 7;
    const int h  = (l >> 3) & 3;
    const int b  = l >> 5;
    const int q0 = qt * 64;
    const size_t base  = ((size_t)b * N_) * D_ + h * HD_;    // q/k/ctx
    const size_t vbase = ((size_t)(b * H_ + h) * HD_) * N_;  // Vt rows=d, cols=key

    const int tid = threadIdx.x;
    const int lane = tid & 63;
    const int w = tid >> 6;
    const int fr = lane & 15, quad = lane >> 4;

    // Q fragments direct from global (one-time, 16B aligned, L2-hot)
    short8 aq[2];
    #pragma unroll
    for (int ks = 0; ks < 2; ++ks)
        aq[ks] = *(const short8*)((const unsigned short*)q + base
                   + (size_t)(q0 + w * 16 + fr) * D_ + (ks * 4 + quad) * 8);

    floatx4 O[4] = {};
    float mrun[4], lrun[4];
    #pragma unroll
    for (int r = 0; r < 4; ++r) { mrun[r] = -1e30f; lrun[r] = 0.f; }

    const int srow = tid >> 2, sc = tid & 3;
    const unsigned short* kp = (const unsigned short*)k + base + (size_t)srow * D_ + sc * 16;
    const unsigned short* vp = (const unsigned short*)vt + vbase + (size_t)srow * N_ + sc * 16;
    const float C1 = 0.125f * 1.44269504f;  // scale * log2(e)

    for (int kt = 0; kt < 8; ++kt) {
        __syncthreads();
        {
            const unsigned short* srck = kp + (size_t)(kt * 64) * D_;
            *(short8*)&Ks[((sc * 2 + 0) * 64 + srow) * 8] = *(const short8*)(srck);
            *(short8*)&Ks[((sc * 2 + 1) * 64 + srow) * 8] = *(const short8*)(srck + 8);
            const unsigned short* srcv = vp + kt * 64;
            *(short8*)&Vs[((sc * 2 + 0) * 64 + srow) * 8] = *(const short8*)(srcv);
            *(short8*)&Vs[((sc * 2 + 1) * 64 + srow) * 8] = *(const short8*)(srcv + 8);
        }
        __syncthreads();

        floatx4 S[4] = {};
        __builtin_amdgcn_s_setprio(1);
        #pragma unroll
        for (int in = 0; in < 4; ++in) {
            #pragma unroll
            for (int ks = 0; ks < 2; ++ks) {
                short8 bk = *(const short8*)&Ks[((ks * 4 + quad) * 64 + in * 16 + fr) * 8];
                S[in] = __builtin_amdgcn_mfma_f32_16x16x32_bf16(aq[ks], bk, S[in], 0, 0, 0);
            }
        }
        __builtin_amdgcn_s_setprio(0);

        #pragma unroll
        for (int r = 0; r < 4; ++r) {
            float mloc = fmaxf(fmaxf(S[0][r], S[1][r]), fmaxf(S[2][r], S[3][r]));
            #pragma unroll
            for (int off = 1; off < 16; off <<= 1) mloc = fmaxf(mloc, __shfl_xor(mloc, off, 64));
            float mnew = fmaxf(mrun[r], mloc);
            float mc = mnew * C1;
            float alpha = exp2f(mrun[r] * C1 - mc);
            float rs = 0.f;
            #pragma unroll
            for (int in = 0; in < 4; ++in) {
                float p = exp2f(S[in][r] * C1 - mc);
                S[in][r] = p;
                rs += p;
            }
            #pragma unroll
            for (int off = 1; off < 16; off <<= 1) rs += __shfl_xor(rs, off, 64);
            lrun[r] = lrun[r] * alpha + rs;
            mrun[r] = mnew;
            #pragma unroll
            for (int in = 0; in < 4; ++in) O[in][r] *= alpha;
        }

        #pragma unroll
        for (int in = 0; in < 4; ++in)
            #pragma unroll
            for (int r = 0; r < 4; ++r)
                Ps[(w * 16 + quad * 4 + r) * 72 + in * 16 + fr] = __float2bfloat16(S[in][r]);
        short8 pa[2];
        #pragma unroll
        for (int ks = 0; ks < 2; ++ks)
            pa[ks] = *(const short8*)&Ps[(w * 16 + fr) * 72 + ks * 32 + quad * 8];

        __builtin_amdgcn_s_setprio(1);
        #pragma unroll
        for (int in = 0; in < 4; ++in) {
            #pragma unroll
            for (int ks = 0; ks < 2; ++ks) {
                short8 bv = *(const short8*)&Vs[((ks * 4 + quad) * 64 + in * 16 + fr) * 8];
                O[in] = __builtin_amdgcn_mfma_f32_16x16x32_bf16(pa[ks], bv, O[in], 0, 0, 0);
            }
        }
        __builtin_amdgcn_s_setprio(0);
    }

    #pragma unroll
    for (int r = 0; r < 4; ++r) {
        const float inv = 1.f / lrun[r];
        const int row = q0 + w * 16 + quad * 4 + r;
        #pragma unroll
        for (int in = 0; in < 4; ++in)
            ctx[base + (size_t)row * D_ + in * 16 + fr] = __float2bfloat16(O[in][r] * inv);
    }
}

// ---------------------------------------------------------------------------
// Mean-pool stage 2 + logits. grid B, block 256. out fp32 (B,2).
// ---------------------------------------------------------------------------
__global__ __launch_bounds__(256)
void logits_k(const float* __restrict__ partial, const float* __restrict__ Wc,
              const float* __restrict__ bc, float* __restrict__ out)
{
    __shared__ float pl[256];
    __shared__ float red[256];
    int b = blockIdx.x, c = threadIdx.x;
    float s = 0.f;
    for (int ch = 0; ch < 8; ++ch) s += partial[((size_t)b * 8 + ch) * D_ + c];
    pl[c] = s * (1.f / 512.f);
    __syncthreads();
    int o = c >> 7, cc = c & 127;
    red[c] = pl[cc] * Wc[o * 256 + cc] + pl[cc + 128] * Wc[o * 256 + cc + 128];
    __syncthreads();
    for (int st = 64; st > 0; st >>= 1) { if (cc < st) red[c] += red[c + st]; __syncthreads(); }
    if (cc == 0) out[b * 2 + o] = red[c] + bc[o];
}

// ---------------------------------------------------------------------------
extern "C" void kernel_launch(void* const* d_in, const int* in_sizes, int n_in,
                              void* d_out, int out_size, void* d_ws, size_t ws_size,
                              hipStream_t stream)
{
    const float* x   = (const float*)d_in[0];
    const float* y   = (const float*)d_in[1];
    // d_in[2] = z, unused by the reference
    const float* Wr  = (const float*)d_in[3];
    const float* br  = (const float*)d_in[4];
    const float* Wf  = (const float*)d_in[5];
    const float* bfv = (const float*)d_in[6];
    const float* gx  = (const float*)d_in[7];
    const float* bx  = (const float*)d_in[8];
    const float* gy  = (const float*)d_in[9];
    const float* by  = (const float*)d_in[10];
    const float* Wq  = (const float*)d_in[11];
    const float* bq  = (const float*)d_in[12];
    const float* Wk  = (const float*)d_in[13];
    const float* bk  = (const float*)d_in[14];
    const float* Wv  = (const float*)d_in[15];
    const float* bv  = (const float*)d_in[16];
    const float* Wo  = (const float*)d_in[17];
    const float* bo  = (const float*)d_in[18];
    const float* gm  = (const float*)d_in[19];
    const float* bm  = (const float*)d_in[20];
    const float* W1  = (const float*)d_in[21];
    const float* b1  = (const float*)d_in[22];
    const float* W2  = (const float*)d_in[23];
    const float* b2  = (const float*)d_in[24];
    const float* Wc  = (const float*)d_in[25];
    const float* bc  = (const float*)d_in[26];

    bf16* ws = (bf16*)d_ws;
    const size_t S = (size_t)B_ * N_ * D_;          // 8,388,608 elems
    bf16*  wb   = ws;                                // weights: 778,240 elems
    float* pe   = (float*)(ws + 778240);             // 131,072 floats
    float* part = pe + 131072;                       // 131,072 floats
    bf16*  bA   = ws + 778240 + 4 * 131072;          // xp
    bf16*  bB   = bA + S;                            // yp -> final x_mlp
    bf16*  bC   = bB + S;                            // q  -> ctx (in-place)
    bf16*  bD   = bC + S;                            // k  -> x_res
    bf16*  bE   = bD + S;                            // Vt -> mlp hidden

    bf16* Wrb = wb;                                  // 256 x 800
    bf16* Wfb = wb + 256 * 800;                      // 256 x 704
    bf16* Wqb = Wfb + 256 * 704;
    bf16* Wkb = Wqb + 65536;
    bf16* Wvb = Wkb + 65536;
    bf16* Wob = Wvb + 65536;
    bf16* W1b = Wob + 65536;
    bf16* W2b = W1b + 65536;

    const int M = B_ * N_; // 32768 rows
    dim3 blk(256);
    dim3 grp(M / 64);                                // 512 row-panel blocks

    // constants: PE table + weight conversion
    pe_k<<<N_, blk, 0, stream>>>(pe);
    convw_k<<<dim3(100, 8), blk, 0, stream>>>(Wr, Wf, Wq, Wk, Wv, Wo, W1, W2, wb);

    // xp = LN(x @ Wr.T + br + pe)   [fp32 A staged in-kernel, LN fused]
    gemm_rp_t<true><<<grp, blk, 0, stream>>>(nullptr, x, 0, 769, Wrb, 800,
        br, nullptr, pe, gx, bx, bA, nullptr, 800, 0, 0);
    // yp = LN(y @ Wf.T + bf + pe)
    gemm_rp_t<true><<<grp, blk, 0, stream>>>(nullptr, y, 0, 674, Wfb, 704,
        bfv, nullptr, pe, gy, by, bB, nullptr, 704, 0, 0);
    // q, k, v (v written transposed per (b,h): Vt[d][key])
    gemm_rp_t<false><<<grp, blk, 0, stream>>>(bA, nullptr, 256, 256, Wqb, 256,
        bq, nullptr, nullptr, nullptr, nullptr, bC, nullptr, 256, 0, 0);
    gemm_rp_t<false><<<grp, blk, 0, stream>>>(bB, nullptr, 256, 256, Wkb, 256,
        bk, nullptr, nullptr, nullptr, nullptr, bD, nullptr, 256, 0, 0);
    gemm_rp_t<false><<<grp, blk, 0, stream>>>(bB, nullptr, 256, 256, Wvb, 256,
        bv, nullptr, nullptr, nullptr, nullptr, bE, nullptr, 256, 0, 1);
    // attention -> ctx (in-place over q)
    attn_k<<<B_ * H_ * 8, blk, 0, stream>>>(bC, bD, bE, bC);
    // x_res = LN(xp + ctx @ Wo.T + bo)   [residual + LN fused]
    gemm_rp_t<false><<<grp, blk, 0, stream>>>(bC, nullptr, 256, 256, Wob, 256,
        bo, bA, nullptr, gm, bm, bD, nullptr, 256, 0, 0);
    // mlp
    gemm_rp_t<false><<<grp, blk, 0, stream>>>(bD, nullptr, 256, 256, W1b, 256,
        b1, nullptr, nullptr, nullptr, nullptr, bE, nullptr, 256, 1, 0);
    gemm_rp_t<false><<<grp, blk, 0, stream>>>(bE, nullptr, 256, 256, W2b, 256,
        b2, bD, nullptr, nullptr, nullptr, bB, part, 256, 0, 0);
    // logits
    logits_k<<<B_, blk, 0, stream>>>(part, Wc, bc, (float*)d_out);
}